// Round 7
// baseline (319.233 us; speedup 1.0000x reference)
//
#include <hip/hip_runtime.h>
#include <math.h>

// ---------------------------------------------------------------------------
// GCN 3-layer inference. bf16 data path, fp32 accumulation.
// CSR build via LDS-multisplit radix partition (dense global writes).
// gemm128 = MFMA bf16 (LDS-free: per-wave 16x128 tile, frag-packed W).
// agg kernels: register-pipelined 8-edge gather groups, u32 saddr addressing.
// agg identity: out[n] = dinv[n]*( Xs[n] + sum_e Xs[col] ),  Xs = dinv.*(A@W)
// ---------------------------------------------------------------------------

#define CSHIFT 9
#define CSZ 512         // nodes per coarse bucket
#define PCHUNK 8192     // edges per k_part1 block

typedef unsigned short u16;
typedef unsigned int u32;
typedef unsigned char u8;
typedef float f32x4 __attribute__((ext_vector_type(4)));
typedef short s16x8 __attribute__((ext_vector_type(8)));

__device__ inline float bflo(u32 u) { return __uint_as_float(u << 16); }
__device__ inline float bfhi(u32 u) { return __uint_as_float(u & 0xffff0000u); }
__device__ inline u16 f2bf(float f) {  // RNE
    u32 b = __float_as_uint(f);
    b += 0x7fff + ((b >> 16) & 1);
    return (u16)(b >> 16);
}
__device__ inline u32 pack2(float lo, float hi) {
    return (u32)f2bf(lo) | ((u32)f2bf(hi) << 16);
}

// ------------------------------- CSR build ---------------------------------

__global__ __launch_bounds__(256) void k_hist1(const int* __restrict__ dst,
                                               int* __restrict__ hist1,
                                               int E, int NB) {
    __shared__ int h[256];
    int t = threadIdx.x;
    h[t] = 0;
    __syncthreads();
    for (int i = blockIdx.x * 256 * 16 + t; i < min(E, (blockIdx.x + 1) * 256 * 16);
         i += 256)
        atomicAdd(&h[dst[i] >> CSHIFT], 1);
    __syncthreads();
    if (t < NB && h[t]) atomicAdd(&hist1[t], h[t]);
}

__global__ __launch_bounds__(256) void k_scan1(const int* __restrict__ hist1,
                                               int* __restrict__ base1,
                                               int* __restrict__ cur1,
                                               int NB, int E) {
    __shared__ int sc[256];
    int t = threadIdx.x;
    int v = (t < NB) ? hist1[t] : 0;
    sc[t] = v;
    __syncthreads();
    for (int d = 1; d < 256; d <<= 1) {
        int add = (t >= d) ? sc[t - d] : 0;
        __syncthreads();
        sc[t] += add;
        __syncthreads();
    }
    if (t < NB) {
        int excl = sc[t] - v;
        base1[t] = excl;
        cur1[t] = excl;
    }
    if (t == 0) base1[NB] = E;
}

__global__ __launch_bounds__(256) void k_part1(const int* __restrict__ src,
                                               const int* __restrict__ dst,
                                               int* __restrict__ cur1,
                                               u32* __restrict__ bkt,
                                               int E, int NB) {
    __shared__ u32 stage[PCHUNK];
    __shared__ u8 sbin[PCHUNK];
    __shared__ int cnt[256];
    __shared__ int lbase[256];
    __shared__ int lcur[256];
    __shared__ int gb[256];
    int t = threadIdx.x;
    int base = blockIdx.x * PCHUNK;
    int n = min(PCHUNK, E - base);
    cnt[t] = 0;
    __syncthreads();
    for (int i = t; i < n; i += 256) atomicAdd(&cnt[dst[base + i] >> CSHIFT], 1);
    __syncthreads();
    int v = cnt[t];
    lbase[t] = v;
    __syncthreads();
    for (int d = 1; d < 256; d <<= 1) {
        int add = (t >= d) ? lbase[t - d] : 0;
        __syncthreads();
        lbase[t] += add;
        __syncthreads();
    }
    {
        int excl = lbase[t] - v;
        __syncthreads();
        lbase[t] = excl;
        lcur[t] = excl;
        if (t < NB && v) gb[t] = atomicAdd(&cur1[t], v);
    }
    __syncthreads();
    for (int i = t; i < n; i += 256) {
        int d = dst[base + i];
        int s = src[base + i];
        int bin = d >> CSHIFT;
        int p = atomicAdd(&lcur[bin], 1);
        stage[p] = ((u32)s << CSHIFT) | (u32)(d & (CSZ - 1));
        sbin[p] = (u8)bin;
    }
    __syncthreads();
    for (int k = t; k < n; k += 256) {
        int bin = sbin[k];
        bkt[gb[bin] + (k - lbase[bin])] = stage[k];
    }
}

__global__ __launch_bounds__(256) void k_csr(const u32* __restrict__ bkt,
                                             const int* __restrict__ base1,
                                             int* __restrict__ col,
                                             int* __restrict__ row,
                                             float* __restrict__ dinv,
                                             int N, int E) {
    __shared__ int deg[CSZ];
    __shared__ int cur[CSZ];
    __shared__ int sc[256];
    int b = blockIdx.x;
    int t = threadIdx.x;
    int start = base1[b];
    int end = base1[b + 1];
    int nbase = b << CSHIFT;
    deg[t] = 0;
    deg[t + 256] = 0;
    __syncthreads();
    for (int i = start + t; i < end; i += 256)
        atomicAdd(&deg[bkt[i] & (CSZ - 1)], 1);
    __syncthreads();
    int d0 = deg[2 * t], d1 = deg[2 * t + 1];
    int s = d0 + d1;
    sc[t] = s;
    __syncthreads();
    for (int d = 1; d < 256; d <<= 1) {
        int add = (t >= d) ? sc[t - d] : 0;
        __syncthreads();
        sc[t] += add;
        __syncthreads();
    }
    int excl = sc[t] - s;
    cur[2 * t] = excl;
    cur[2 * t + 1] = excl + d0;
    int n0 = nbase + 2 * t, n1 = n0 + 1;
    if (n0 < N) { row[n0] = start + excl;      dinv[n0] = rsqrtf((float)(d0 + 1)); }
    if (n1 < N) { row[n1] = start + excl + d0; dinv[n1] = rsqrtf((float)(d1 + 1)); }
    __syncthreads();
    for (int i = start + t; i < end; i += 256) {
        u32 v = bkt[i];
        int p = start + atomicAdd(&cur[v & (CSZ - 1)], 1);
        col[p] = (int)(v >> CSHIFT);
    }
    if (b == 0 && t == 0) row[N] = E;
}

// --------------------------------- GEMMs -----------------------------------

// Pack W[128x128] fp32 into bf16 MFMA B-fragment order.
__global__ __launch_bounds__(256) void k_packW(const float* __restrict__ W,
                                               u16* __restrict__ Wpk) {
    int g = blockIdx.x * 256 + threadIdx.x;  // 0..16383
    int j = g & 7;
    int l = (g >> 3) & 63;
    int f = g >> 9;         // 0..31
    int ct = f & 7, ks = f >> 3;
    int krow = ks * 32 + ((l >> 4) << 3) + j;
    int wcol = ct * 16 + (l & 15);
    Wpk[g] = f2bf(W[krow * 128 + wcol]);
}

// C[r](bf16) = dinv[r] * (A[r] @ W).  MFMA 16x16x32 bf16, LDS-free.
template <bool AFP32>
__global__ __launch_bounds__(256) void k_gemm128m(const void* __restrict__ Av,
                                                  const u16* __restrict__ Wpk,
                                                  u16* __restrict__ C,
                                                  const float* __restrict__ dinv,
                                                  int M) {
    int tid = threadIdx.x;
    int wv = blockIdx.x * 4 + (tid >> 6);
    int rowbase = wv * 16;
    if (rowbase >= M) return;
    int l = tid & 63;
    int r = l & 15, hi = l >> 4;

    f32x4 acc[8];
#pragma unroll
    for (int ct = 0; ct < 8; ++ct) acc[ct] = (f32x4)(0.f);

    const uint4* wp = (const uint4*)Wpk;
#pragma unroll
    for (int ks = 0; ks < 4; ++ks) {
        s16x8 afrag;
        int abase = (rowbase + r) * 128 + ks * 32 + hi * 8;
        if (AFP32) {
            const float* A = (const float*)Av;
            float4 a0 = *(const float4*)&A[abase];
            float4 a1 = *(const float4*)&A[abase + 4];
            u32 p0 = pack2(a0.x, a0.y), p1 = pack2(a0.z, a0.w);
            u32 p2 = pack2(a1.x, a1.y), p3 = pack2(a1.z, a1.w);
            uint4 u = make_uint4(p0, p1, p2, p3);
            afrag = *(s16x8*)&u;
        } else {
            const u16* A = (const u16*)Av;
            uint4 u = *(const uint4*)&A[abase];
            afrag = *(s16x8*)&u;
        }
#pragma unroll
        for (int ct = 0; ct < 8; ++ct) {
            uint4 b = wp[(ks * 8 + ct) * 64 + l];
            s16x8 bfrag = *(s16x8*)&b;
            acc[ct] = __builtin_amdgcn_mfma_f32_16x16x32_bf16(afrag, bfrag, acc[ct], 0, 0, 0);
        }
    }
    float dv[4];
#pragma unroll
    for (int reg = 0; reg < 4; ++reg) dv[reg] = dinv[rowbase + 4 * hi + reg];
#pragma unroll
    for (int ct = 0; ct < 8; ++ct) {
#pragma unroll
        for (int reg = 0; reg < 4; ++reg) {
            int orow = rowbase + 4 * hi + reg;
            C[(size_t)orow * 128 + ct * 16 + r] = f2bf(dv[reg] * acc[ct][reg]);
        }
    }
}

// C[r](bf16) = dinv[r] * (A[r] @ W), A: Mx128 bf16, W: 128x40 fp32.
__global__ __launch_bounds__(256) void k_gemm40(const u16* __restrict__ A,
                                                const float* __restrict__ W,
                                                u16* __restrict__ C,
                                                const float* __restrict__ dinv,
                                                int M) {
    __shared__ float Ws[128 * 40];
    for (int i = threadIdx.x; i < 128 * 40; i += 256) Ws[i] = W[i];
    __syncthreads();
    int r0 = blockIdx.x * 512 + threadIdx.x;
    int r1 = r0 + 256;
    float acc0[40], acc1[40];
#pragma unroll
    for (int c = 0; c < 40; ++c) { acc0[c] = 0.f; acc1[c] = 0.f; }
    const uint2* x0 = (const uint2*)(A + (size_t)min(r0, M - 1) * 128);
    const uint2* x1 = (const uint2*)(A + (size_t)min(r1, M - 1) * 128);
    for (int kb = 0; kb < 32; ++kb) {
        uint2 ua = x0[kb];
        uint2 ub = x1[kb];
        float a0x = bflo(ua.x), a0y = bfhi(ua.x), a0z = bflo(ua.y), a0w = bfhi(ua.y);
        float a1x = bflo(ub.x), a1y = bfhi(ub.x), a1z = bflo(ub.y), a1w = bfhi(ub.y);
        const float* wr = &Ws[kb * 160];
#pragma unroll
        for (int c4 = 0; c4 < 10; ++c4) {
            float4 wk0 = *(const float4*)&wr[c4 * 4];
            float4 wk1 = *(const float4*)&wr[40 + c4 * 4];
            float4 wk2 = *(const float4*)&wr[80 + c4 * 4];
            float4 wk3 = *(const float4*)&wr[120 + c4 * 4];
            int c = c4 * 4;
            acc0[c+0] = fmaf(a0x,wk0.x, fmaf(a0y,wk1.x, fmaf(a0z,wk2.x, fmaf(a0w,wk3.x, acc0[c+0]))));
            acc0[c+1] = fmaf(a0x,wk0.y, fmaf(a0y,wk1.y, fmaf(a0z,wk2.y, fmaf(a0w,wk3.y, acc0[c+1]))));
            acc0[c+2] = fmaf(a0x,wk0.z, fmaf(a0y,wk1.z, fmaf(a0z,wk2.z, fmaf(a0w,wk3.z, acc0[c+2]))));
            acc0[c+3] = fmaf(a0x,wk0.w, fmaf(a0y,wk1.w, fmaf(a0z,wk2.w, fmaf(a0w,wk3.w, acc0[c+3]))));
            acc1[c+0] = fmaf(a1x,wk0.x, fmaf(a1y,wk1.x, fmaf(a1z,wk2.x, fmaf(a1w,wk3.x, acc1[c+0]))));
            acc1[c+1] = fmaf(a1x,wk0.y, fmaf(a1y,wk1.y, fmaf(a1z,wk2.y, fmaf(a1w,wk3.y, acc1[c+1]))));
            acc1[c+2] = fmaf(a1x,wk0.z, fmaf(a1y,wk1.z, fmaf(a1z,wk2.z, fmaf(a1w,wk3.z, acc1[c+2]))));
            acc1[c+3] = fmaf(a1x,wk0.w, fmaf(a1y,wk1.w, fmaf(a1z,wk2.w, fmaf(a1w,wk3.w, acc1[c+3]))));
        }
    }
    if (r0 < M) {
        float s = dinv[r0];
        u32* crow = (u32*)(C + (size_t)r0 * 40);
#pragma unroll
        for (int c2 = 0; c2 < 20; ++c2) crow[c2] = pack2(s * acc0[2*c2], s * acc0[2*c2+1]);
    }
    if (r1 < M) {
        float s = dinv[r1];
        u32* crow = (u32*)(C + (size_t)r1 * 40);
#pragma unroll
        for (int c2 = 0; c2 < 20; ++c2) crow[c2] = pack2(s * acc1[2*c2], s * acc1[2*c2+1]);
    }
}

// ------------------------------ aggregation --------------------------------

// d=128 bf16 gather-sum; 2 nodes/wave (32 lanes x 8 B); register-pipelined
// 8-edge groups; u32 saddr addressing; masked tail; fused bias+BN+ReLU.
__global__ __launch_bounds__(256) void k_agg128(const u16* __restrict__ X,
                                                u16* __restrict__ Y,
                                                const int* __restrict__ row,
                                                const int* __restrict__ col,
                                                const float* __restrict__ dinv,
                                                const float* __restrict__ bias,
                                                const float* __restrict__ g,
                                                const float* __restrict__ be,
                                                const float* __restrict__ mean,
                                                const float* __restrict__ var,
                                                int n) {
    int tid = threadIdx.x;
    int wid = tid >> 6, lane = tid & 63;
    int half = lane >> 5, l5 = lane & 31;
    int node = (blockIdx.x * 4 + wid) * 2 + half;
    bool valid = node < n;
    int nc = valid ? node : (n - 1);
    const char* xb = (const char*)X;     // row stride 256 B
    const char* cb = (const char*)col;
    u32 lo8 = (u32)l5 * 8u;
    int s = row[nc], e = row[nc + 1];

    float ac[4][4];
#pragma unroll
    for (int q = 0; q < 4; ++q)
#pragma unroll
        for (int i = 0; i < 4; ++i) ac[q][i] = 0.f;
    {   // self (pre-scaled)
        uint2 sv = *(const uint2*)(xb + (((u32)nc) << 8) + lo8);
        ac[0][0] = bflo(sv.x); ac[0][1] = bfhi(sv.x);
        ac[0][2] = bflo(sv.y); ac[0][3] = bfhi(sv.y);
    }

#define ACCQ(v, q) { ac[q][0] += bflo((v).x); ac[q][1] += bfhi((v).x); \
                     ac[q][2] += bflo((v).y); ac[q][3] += bfhi((v).y); }

    int nfull = (e - s) >> 3;
    int j = s;
    if (nfull > 0) {
        uint2 cur[8], nxt[8];
        u32 coff = (u32)j << 2;
#pragma unroll
        for (int k = 0; k < 8; ++k) {
            int c = *(const int*)(cb + coff + k * 4);
            cur[k] = *(const uint2*)(xb + (((u32)c) << 8) + lo8);
        }
        for (int gi = 1; gi < nfull; ++gi) {
            coff += 32;
#pragma unroll
            for (int k = 0; k < 8; ++k) {
                int c = *(const int*)(cb + coff + k * 4);
                nxt[k] = *(const uint2*)(xb + (((u32)c) << 8) + lo8);
            }
#pragma unroll
            for (int k = 0; k < 8; ++k) ACCQ(cur[k], k & 3);
#pragma unroll
            for (int k = 0; k < 8; ++k) cur[k] = nxt[k];
        }
#pragma unroll
        for (int k = 0; k < 8; ++k) ACCQ(cur[k], k & 3);
        j += nfull * 8;
    }
    {   // masked tail group (<=7 edges)
        int rem = e - j;
        if (rem > 0) {
            u32 coff = (u32)j << 2;
#pragma unroll
            for (int k = 0; k < 8; ++k) {
                uint2 v = make_uint2(0u, 0u);
                if (k < rem) {
                    int c = *(const int*)(cb + coff + k * 4);
                    v = *(const uint2*)(xb + (((u32)c) << 8) + lo8);
                }
                ACCQ(v, k & 3);
            }
        }
    }
#undef ACCQ

    float dv = dinv[nc];
    float s0 = dv * ((ac[0][0] + ac[1][0]) + (ac[2][0] + ac[3][0]));
    float s1 = dv * ((ac[0][1] + ac[1][1]) + (ac[2][1] + ac[3][1]));
    float s2 = dv * ((ac[0][2] + ac[1][2]) + (ac[2][2] + ac[3][2]));
    float s3 = dv * ((ac[0][3] + ac[1][3]) + (ac[2][3] + ac[3][3]));
    float4 g4 = ((const float4*)g)[l5];
    float4 be4 = ((const float4*)be)[l5];
    float4 m4 = ((const float4*)mean)[l5];
    float4 v4 = ((const float4*)var)[l5];
    float4 bi4 = ((const float4*)bias)[l5];
    float sc0 = g4.x * rsqrtf(v4.x + 1e-5f);
    float sc1 = g4.y * rsqrtf(v4.y + 1e-5f);
    float sc2 = g4.z * rsqrtf(v4.z + 1e-5f);
    float sc3 = g4.w * rsqrtf(v4.w + 1e-5f);
    float y0 = fmaxf(fmaf(sc0, s0, fmaf(sc0, bi4.x - m4.x, be4.x)), 0.f);
    float y1 = fmaxf(fmaf(sc1, s1, fmaf(sc1, bi4.y - m4.y, be4.y)), 0.f);
    float y2 = fmaxf(fmaf(sc2, s2, fmaf(sc2, bi4.z - m4.z, be4.z)), 0.f);
    float y3 = fmaxf(fmaf(sc3, s3, fmaf(sc3, bi4.w - m4.w, be4.w)), 0.f);
    if (valid) {
        uint2 o;
        o.x = pack2(y0, y1);
        o.y = pack2(y2, y3);
        ((uint2*)Y)[(size_t)node * 32 + l5] = o;
    }
}

// d=40 bf16 gather-sum + bias + log_softmax; 2 nodes/wave, 20 lanes x 2 feats;
// register-pipelined 8-edge groups; u32 addressing.
__global__ __launch_bounds__(256) void k_agg40(const u16* __restrict__ X,
                                               float* __restrict__ out,
                                               const int* __restrict__ row,
                                               const int* __restrict__ col,
                                               const float* __restrict__ dinv,
                                               const float* __restrict__ b2,
                                               int n) {
    int tid = threadIdx.x;
    int wid = tid >> 6, lane = tid & 63;
    int half = lane >> 5, l5 = lane & 31;
    int node = (blockIdx.x * 4 + wid) * 2 + half;
    bool valid = node < n;
    int nc = valid ? node : (n - 1);
    bool active = l5 < 20;
    const char* xb = (const char*)X;     // row stride 80 B
    const char* cb = (const char*)col;
    u32 lob = (u32)min(l5, 19) * 4u;     // clamped: all lanes load valid bytes
    int s = row[nc], e = row[nc + 1];

    float ac[4][2];
#pragma unroll
    for (int q = 0; q < 4; ++q) { ac[q][0] = 0.f; ac[q][1] = 0.f; }
    {
        u32 ro = (((u32)nc) << 6) + (((u32)nc) << 4);
        u32 sv = *(const u32*)(xb + ro + lob);
        ac[0][0] = bflo(sv); ac[0][1] = bfhi(sv);
    }

#define ACCQ40(v, q) { ac[q][0] += bflo(v); ac[q][1] += bfhi(v); }

    int nfull = (e - s) >> 3;
    int j = s;
    if (nfull > 0) {
        u32 cur[8], nxt[8];
        u32 coff = (u32)j << 2;
#pragma unroll
        for (int k = 0; k < 8; ++k) {
            int c = *(const int*)(cb + coff + k * 4);
            u32 ro = (((u32)c) << 6) + (((u32)c) << 4);
            cur[k] = *(const u32*)(xb + ro + lob);
        }
        for (int gi = 1; gi < nfull; ++gi) {
            coff += 32;
#pragma unroll
            for (int k = 0; k < 8; ++k) {
                int c = *(const int*)(cb + coff + k * 4);
                u32 ro = (((u32)c) << 6) + (((u32)c) << 4);
                nxt[k] = *(const u32*)(xb + ro + lob);
            }
#pragma unroll
            for (int k = 0; k < 8; ++k) ACCQ40(cur[k], k & 3);
#pragma unroll
            for (int k = 0; k < 8; ++k) cur[k] = nxt[k];
        }
#pragma unroll
        for (int k = 0; k < 8; ++k) ACCQ40(cur[k], k & 3);
        j += nfull * 8;
    }
    {
        int rem = e - j;
        if (rem > 0) {
            u32 coff = (u32)j << 2;
#pragma unroll
            for (int k = 0; k < 8; ++k) {
                u32 v = 0u;
                if (k < rem) {
                    int c = *(const int*)(cb + coff + k * 4);
                    u32 ro = (((u32)c) << 6) + (((u32)c) << 4);
                    v = *(const u32*)(xb + ro + lob);
                }
                ACCQ40(v, k & 3);
            }
        }
    }
#undef ACCQ40

    float dv = dinv[nc];
    float ylo = -INFINITY, yhi = -INFINITY;
    if (active) {
        float2 bb = ((const float2*)b2)[l5];
        ylo = fmaf(dv, (ac[0][0] + ac[1][0]) + (ac[2][0] + ac[3][0]), bb.x);
        yhi = fmaf(dv, (ac[0][1] + ac[1][1]) + (ac[2][1] + ac[3][1]), bb.y);
    }
    float m = fmaxf(ylo, yhi);
#pragma unroll
    for (int d = 16; d; d >>= 1) m = fmaxf(m, __shfl_xor(m, d));
    float ex = active ? (__expf(ylo - m) + __expf(yhi - m)) : 0.f;
#pragma unroll
    for (int d = 16; d; d >>= 1) ex += __shfl_xor(ex, d);
    if (valid && active) {
        float lse = m + __logf(ex);
        ((float2*)out)[(size_t)node * 20 + l5] = make_float2(ylo - lse, yhi - lse);
    }
}

// --------------------------------- launch ----------------------------------

extern "C" void kernel_launch(void* const* d_in, const int* in_sizes, int n_in,
                              void* d_out, int out_size, void* d_ws, size_t ws_size,
                              hipStream_t stream) {
    const float* x   = (const float*)d_in[0];
    const int*   ei  = (const int*)d_in[1];
    const float* W0  = (const float*)d_in[2];
    const float* b0  = (const float*)d_in[3];
    const float* W1  = (const float*)d_in[4];
    const float* b1  = (const float*)d_in[5];
    const float* W2  = (const float*)d_in[6];
    const float* b2  = (const float*)d_in[7];
    const float* g0  = (const float*)d_in[8];
    const float* be0 = (const float*)d_in[9];
    const float* m0  = (const float*)d_in[10];
    const float* v0  = (const float*)d_in[11];
    const float* g1  = (const float*)d_in[12];
    const float* be1 = (const float*)d_in[13];
    const float* m1  = (const float*)d_in[14];
    const float* v1  = (const float*)d_in[15];
    float* out = (float*)d_out;

    int N = in_sizes[0] / 128;
    int E = in_sizes[1] / 2;
    const int* src = ei;
    const int* dst = ei + E;

    int NB = (N + CSZ - 1) / CSZ;

    char* ws = (char*)d_ws;
    size_t off = 0;
    auto alloc = [&](size_t bytes) -> char* {
        char* p = ws + off;
        off += (bytes + 255) & ~(size_t)255;
        return p;
    };
    u16*   XsA   = (u16*)alloc((size_t)N * 128 * 2);
    u16*   hB    = (u16*)alloc((size_t)N * 128 * 2);
    u16*   bufC  = (u16*)alloc((size_t)N * 40 * 2);
    int*   col   = (int*)alloc((size_t)E * 4 + 64);
    int*   row   = (int*)alloc((size_t)(N + 1) * 4);
    float* dinv  = (float*)alloc((size_t)N * 4);
    int*   hist1 = (int*)alloc((size_t)(NB + 1) * 4);
    int*   base1 = (int*)alloc((size_t)(NB + 1) * 4);
    int*   cur1  = (int*)alloc((size_t)(NB + 1) * 4);
    u16*   Wpk0  = (u16*)alloc(128 * 128 * 2);
    u16*   Wpk1  = (u16*)alloc(128 * 128 * 2);
    u32*   bkt   = (u32*)XsA;  // alias: bkt dead before gemm0 writes XsA

    hipMemsetAsync(hist1, 0, (size_t)(NB + 1) * 4, stream);
    k_hist1<<<(E + 4095) / 4096, 256, 0, stream>>>(dst, hist1, E, NB);
    k_scan1<<<1, 256, 0, stream>>>(hist1, base1, cur1, NB, E);
    k_part1<<<(E + PCHUNK - 1) / PCHUNK, 256, 0, stream>>>(src, dst, cur1, bkt, E, NB);
    k_csr<<<NB, 256, 0, stream>>>(bkt, base1, col, row, dinv, N, E);
    k_packW<<<64, 256, 0, stream>>>(W0, Wpk0);
    k_packW<<<64, 256, 0, stream>>>(W1, Wpk1);

    int gemmGrid = ((N + 15) / 16 + 3) / 4;
    k_gemm128m<true><<<gemmGrid, 256, 0, stream>>>(x, Wpk0, XsA, dinv, N);
    k_agg128<<<(N + 7) / 8, 256, 0, stream>>>(XsA, hB, row, col, dinv, b0, g0, be0, m0, v0, N);
    k_gemm128m<false><<<gemmGrid, 256, 0, stream>>>(hB, Wpk1, XsA, dinv, N);
    k_agg128<<<(N + 7) / 8, 256, 0, stream>>>(XsA, hB, row, col, dinv, b1, g1, be1, m1, v1, N);
    k_gemm40<<<(N + 511) / 512, 256, 0, stream>>>(hB, W2, bufC, dinv, N);
    k_agg40<<<(N + 7) / 8, 256, 0, stream>>>(bufC, out, row, col, dinv, b2, N);
}

// Round 8
// 284.764 us; speedup vs baseline: 1.1210x; 1.1210x over previous
//
#include <hip/hip_runtime.h>
#include <math.h>

// ---------------------------------------------------------------------------
// GCN 3-layer inference. bf16 data path, fp32 accumulation.
// CSR build via LDS-multisplit radix partition (dense global writes).
// Layer fusion: agg+BN+ReLU (16 nodes/block, 8 waves) -> LDS -> MFMA GEMM.
//   gemm0 (x@W0, MFMA, LDS-free)  -> XsA
//   fused<8>: agg(XsA)+bn0+relu -> @W1*dinv -> XsB
//   fused<3>: agg(XsB)+bn1+relu -> @W2*dinv -> bufC (48-pad, 40 stored)
//   agg40: gather + b2 + log_softmax -> out
// agg identity: out[n] = dinv[n]*( Xs[n] + sum_e Xs[col] ),  Xs = dinv.*(A@W)
// agg128-path is at the cross-XCD fabric roofline (8 XCD x 25.6MB compulsory
// at ~3.4 TB/s); this round removes the GEMM round-trips around it.
// ---------------------------------------------------------------------------

#define CSHIFT 9
#define CSZ 512
#define PCHUNK 8192

typedef unsigned short u16;
typedef unsigned int u32;
typedef unsigned char u8;
typedef float f32x4 __attribute__((ext_vector_type(4)));
typedef short s16x8 __attribute__((ext_vector_type(8)));

__device__ inline float bflo(u32 u) { return __uint_as_float(u << 16); }
__device__ inline float bfhi(u32 u) { return __uint_as_float(u & 0xffff0000u); }
__device__ inline u16 f2bf(float f) {  // RNE
    u32 b = __float_as_uint(f);
    b += 0x7fff + ((b >> 16) & 1);
    return (u16)(b >> 16);
}
__device__ inline u32 pack2(float lo, float hi) {
    return (u32)f2bf(lo) | ((u32)f2bf(hi) << 16);
}

// ------------------------------- CSR build ---------------------------------

__global__ __launch_bounds__(256) void k_hist1(const int* __restrict__ dst,
                                               int* __restrict__ hist1,
                                               int E, int NB) {
    __shared__ int h[256];
    int t = threadIdx.x;
    h[t] = 0;
    __syncthreads();
    for (int i = blockIdx.x * 256 * 16 + t; i < min(E, (blockIdx.x + 1) * 256 * 16);
         i += 256)
        atomicAdd(&h[dst[i] >> CSHIFT], 1);
    __syncthreads();
    if (t < NB && h[t]) atomicAdd(&hist1[t], h[t]);
}

__global__ __launch_bounds__(256) void k_scan1(const int* __restrict__ hist1,
                                               int* __restrict__ base1,
                                               int* __restrict__ cur1,
                                               int NB, int E) {
    __shared__ int sc[256];
    int t = threadIdx.x;
    int v = (t < NB) ? hist1[t] : 0;
    sc[t] = v;
    __syncthreads();
    for (int d = 1; d < 256; d <<= 1) {
        int add = (t >= d) ? sc[t - d] : 0;
        __syncthreads();
        sc[t] += add;
        __syncthreads();
    }
    if (t < NB) {
        int excl = sc[t] - v;
        base1[t] = excl;
        cur1[t] = excl;
    }
    if (t == 0) base1[NB] = E;
}

__global__ __launch_bounds__(256) void k_part1(const int* __restrict__ src,
                                               const int* __restrict__ dst,
                                               int* __restrict__ cur1,
                                               u32* __restrict__ bkt,
                                               int E, int NB) {
    __shared__ u32 stage[PCHUNK];
    __shared__ u8 sbin[PCHUNK];
    __shared__ int cnt[256];
    __shared__ int lbase[256];
    __shared__ int lcur[256];
    __shared__ int gb[256];
    int t = threadIdx.x;
    int base = blockIdx.x * PCHUNK;
    int n = min(PCHUNK, E - base);
    cnt[t] = 0;
    __syncthreads();
    for (int i = t; i < n; i += 256) atomicAdd(&cnt[dst[base + i] >> CSHIFT], 1);
    __syncthreads();
    int v = cnt[t];
    lbase[t] = v;
    __syncthreads();
    for (int d = 1; d < 256; d <<= 1) {
        int add = (t >= d) ? lbase[t - d] : 0;
        __syncthreads();
        lbase[t] += add;
        __syncthreads();
    }
    {
        int excl = lbase[t] - v;
        __syncthreads();
        lbase[t] = excl;
        lcur[t] = excl;
        if (t < NB && v) gb[t] = atomicAdd(&cur1[t], v);
    }
    __syncthreads();
    for (int i = t; i < n; i += 256) {
        int d = dst[base + i];
        int s = src[base + i];
        int bin = d >> CSHIFT;
        int p = atomicAdd(&lcur[bin], 1);
        stage[p] = ((u32)s << CSHIFT) | (u32)(d & (CSZ - 1));
        sbin[p] = (u8)bin;
    }
    __syncthreads();
    for (int k = t; k < n; k += 256) {
        int bin = sbin[k];
        bkt[gb[bin] + (k - lbase[bin])] = stage[k];
    }
}

__global__ __launch_bounds__(256) void k_csr(const u32* __restrict__ bkt,
                                             const int* __restrict__ base1,
                                             int* __restrict__ col,
                                             int* __restrict__ row,
                                             float* __restrict__ dinv,
                                             int N, int E) {
    __shared__ int deg[CSZ];
    __shared__ int cur[CSZ];
    __shared__ int sc[256];
    int b = blockIdx.x;
    int t = threadIdx.x;
    int start = base1[b];
    int end = base1[b + 1];
    int nbase = b << CSHIFT;
    deg[t] = 0;
    deg[t + 256] = 0;
    __syncthreads();
    for (int i = start + t; i < end; i += 256)
        atomicAdd(&deg[bkt[i] & (CSZ - 1)], 1);
    __syncthreads();
    int d0 = deg[2 * t], d1 = deg[2 * t + 1];
    int s = d0 + d1;
    sc[t] = s;
    __syncthreads();
    for (int d = 1; d < 256; d <<= 1) {
        int add = (t >= d) ? sc[t - d] : 0;
        __syncthreads();
        sc[t] += add;
        __syncthreads();
    }
    int excl = sc[t] - s;
    cur[2 * t] = excl;
    cur[2 * t + 1] = excl + d0;
    int n0 = nbase + 2 * t, n1 = n0 + 1;
    if (n0 < N) { row[n0] = start + excl;      dinv[n0] = rsqrtf((float)(d0 + 1)); }
    if (n1 < N) { row[n1] = start + excl + d0; dinv[n1] = rsqrtf((float)(d1 + 1)); }
    __syncthreads();
    for (int i = start + t; i < end; i += 256) {
        u32 v = bkt[i];
        int p = start + atomicAdd(&cur[v & (CSZ - 1)], 1);
        col[p] = (int)(v >> CSHIFT);
    }
    if (b == 0 && t == 0) row[N] = E;
}

// ------------------------------ weight packing -----------------------------

// W[128x128] fp32 -> bf16 frag order: Wpk[(((ks*8+ct)*64)+l)*8+j]
__global__ __launch_bounds__(256) void k_packW(const float* __restrict__ W,
                                               u16* __restrict__ Wpk) {
    int g = blockIdx.x * 256 + threadIdx.x;  // 0..16383
    int j = g & 7;
    int l = (g >> 3) & 63;
    int f = g >> 9;
    int ct = f & 7, ks = f >> 3;
    int krow = ks * 32 + ((l >> 4) << 3) + j;
    int wcol = ct * 16 + (l & 15);
    Wpk[g] = f2bf(W[krow * 128 + wcol]);
}

// W2[128x40] fp32 -> bf16 frag order padded to 48 cols (3 col-tiles).
__global__ __launch_bounds__(256) void k_packW40(const float* __restrict__ W,
                                                 u16* __restrict__ Wpk) {
    int g = blockIdx.x * 256 + threadIdx.x;  // 0..6143
    if (g >= 12 * 512) return;
    int j = g & 7;
    int l = (g >> 3) & 63;
    int f = g >> 9;          // 0..11
    int ct = f % 3, ks = f / 3;
    int krow = ks * 32 + ((l >> 4) << 3) + j;
    int wcol = ct * 16 + (l & 15);
    Wpk[g] = (wcol < 40) ? f2bf(W[krow * 40 + wcol]) : (u16)0;
}

// ----------------------------- layer-1 GEMM --------------------------------

// XsA[r](bf16) = dinv[r] * (x[r] @ W0). MFMA 16x16x32 bf16, LDS-free, fp32 in.
__global__ __launch_bounds__(256) void k_gemm0(const float* __restrict__ A,
                                               const u16* __restrict__ Wpk,
                                               u16* __restrict__ C,
                                               const float* __restrict__ dinv,
                                               int M) {
    int tid = threadIdx.x;
    int wv = blockIdx.x * 4 + (tid >> 6);
    int rowbase = wv * 16;
    if (rowbase >= M) return;
    int l = tid & 63;
    int r = l & 15, hi = l >> 4;

    f32x4 acc[8];
#pragma unroll
    for (int ct = 0; ct < 8; ++ct) acc[ct] = (f32x4)(0.f);

    const uint4* wp = (const uint4*)Wpk;
#pragma unroll
    for (int ks = 0; ks < 4; ++ks) {
        int abase = (min(rowbase + r, M - 1)) * 128 + ks * 32 + hi * 8;
        float4 a0 = *(const float4*)&A[abase];
        float4 a1 = *(const float4*)&A[abase + 4];
        uint4 u = make_uint4(pack2(a0.x, a0.y), pack2(a0.z, a0.w),
                             pack2(a1.x, a1.y), pack2(a1.z, a1.w));
        s16x8 afrag = *(s16x8*)&u;
#pragma unroll
        for (int ct = 0; ct < 8; ++ct) {
            uint4 b = wp[(ks * 8 + ct) * 64 + l];
            s16x8 bfrag = *(s16x8*)&b;
            acc[ct] = __builtin_amdgcn_mfma_f32_16x16x32_bf16(afrag, bfrag, acc[ct], 0, 0, 0);
        }
    }
    float dv[4];
#pragma unroll
    for (int reg = 0; reg < 4; ++reg) {
        int orow = rowbase + 4 * hi + reg;
        dv[reg] = (orow < M) ? dinv[orow] : 0.f;
    }
#pragma unroll
    for (int ct = 0; ct < 8; ++ct) {
#pragma unroll
        for (int reg = 0; reg < 4; ++reg) {
            int orow = rowbase + 4 * hi + reg;
            if (orow < M)
                C[(size_t)orow * 128 + ct * 16 + r] = f2bf(dv[reg] * acc[ct][reg]);
        }
    }
}

// --------------------------- fused agg + GEMM ------------------------------

// Per block (512 thr, 8 waves): 16 nodes. Phase 1: each half-wave gathers one
// node's 128-d row-sum over neighbors (R6 agg structure), applies bias+BN+ReLU,
// stores bf16 to LDS (XOR-swizzled 16B units). Phase 2: wave w MFMAs col-tile
// ct=w (NCT tiles) against packed W; epilogue scales by dinv, stores bf16.
template <int NCT>
__global__ __launch_bounds__(512) void k_fused(const u16* __restrict__ X,
                                               const u16* __restrict__ Wpk,
                                               u16* __restrict__ O,
                                               const int* __restrict__ row,
                                               const int* __restrict__ col,
                                               const float* __restrict__ dinv,
                                               const float* __restrict__ bias,
                                               const float* __restrict__ g,
                                               const float* __restrict__ be,
                                               const float* __restrict__ mean,
                                               const float* __restrict__ var,
                                               int n, int ostride) {
    __shared__ u32 hl[16][64];
    int tid = threadIdx.x;
    int nl = tid >> 5;            // 0..15 local node
    int l5 = tid & 31;
    int node = blockIdx.x * 16 + nl;
    int nc = min(node, n - 1);
    const uint2* xp = (const uint2*)X;
    int s = row[nc], e = row[nc + 1];

    uint2 v = xp[(size_t)nc * 32 + l5];
    float a0 = bflo(v.x), a1 = bfhi(v.x), a2 = bflo(v.y), a3 = bfhi(v.y);
    float b0 = 0, b1 = 0, b2 = 0, b3 = 0;
    float c0 = 0, c1 = 0, c2 = 0, c3 = 0;
    float d0 = 0, d1 = 0, d2 = 0, d3 = 0;
    int j = s;
    for (; j + 8 <= e; j += 8) {
        int e0 = col[j], e1 = col[j+1], e2 = col[j+2], e3 = col[j+3];
        int e4 = col[j+4], e5 = col[j+5], e6 = col[j+6], e7 = col[j+7];
        uint2 x0 = xp[(size_t)e0 * 32 + l5];
        uint2 x1 = xp[(size_t)e1 * 32 + l5];
        uint2 x2 = xp[(size_t)e2 * 32 + l5];
        uint2 x3 = xp[(size_t)e3 * 32 + l5];
        uint2 x4 = xp[(size_t)e4 * 32 + l5];
        uint2 x5 = xp[(size_t)e5 * 32 + l5];
        uint2 x6 = xp[(size_t)e6 * 32 + l5];
        uint2 x7 = xp[(size_t)e7 * 32 + l5];
        a0 += bflo(x0.x); a1 += bfhi(x0.x); a2 += bflo(x0.y); a3 += bfhi(x0.y);
        b0 += bflo(x1.x); b1 += bfhi(x1.x); b2 += bflo(x1.y); b3 += bfhi(x1.y);
        c0 += bflo(x2.x); c1 += bfhi(x2.x); c2 += bflo(x2.y); c3 += bfhi(x2.y);
        d0 += bflo(x3.x); d1 += bfhi(x3.x); d2 += bflo(x3.y); d3 += bfhi(x3.y);
        a0 += bflo(x4.x); a1 += bfhi(x4.x); a2 += bflo(x4.y); a3 += bfhi(x4.y);
        b0 += bflo(x5.x); b1 += bfhi(x5.x); b2 += bflo(x5.y); b3 += bfhi(x5.y);
        c0 += bflo(x6.x); c1 += bfhi(x6.x); c2 += bflo(x6.y); c3 += bfhi(x6.y);
        d0 += bflo(x7.x); d1 += bfhi(x7.x); d2 += bflo(x7.y); d3 += bfhi(x7.y);
    }
    for (; j + 2 <= e; j += 2) {
        int e0 = col[j], e1 = col[j+1];
        uint2 x0 = xp[(size_t)e0 * 32 + l5];
        uint2 x1 = xp[(size_t)e1 * 32 + l5];
        a0 += bflo(x0.x); a1 += bfhi(x0.x); a2 += bflo(x0.y); a3 += bfhi(x0.y);
        b0 += bflo(x1.x); b1 += bfhi(x1.x); b2 += bflo(x1.y); b3 += bfhi(x1.y);
    }
    if (j < e) {
        uint2 x0 = xp[(size_t)col[j] * 32 + l5];
        c0 += bflo(x0.x); c1 += bfhi(x0.x); c2 += bflo(x0.y); c3 += bfhi(x0.y);
    }
    float dvn = dinv[nc];
    float s0 = dvn * ((a0 + b0) + (c0 + d0));
    float s1 = dvn * ((a1 + b1) + (c1 + d1));
    float s2 = dvn * ((a2 + b2) + (c2 + d2));
    float s3 = dvn * ((a3 + b3) + (c3 + d3));
    float4 g4 = ((const float4*)g)[l5];
    float4 be4 = ((const float4*)be)[l5];
    float4 m4 = ((const float4*)mean)[l5];
    float4 v4 = ((const float4*)var)[l5];
    float4 bi4 = ((const float4*)bias)[l5];
    float sc0 = g4.x * rsqrtf(v4.x + 1e-5f);
    float sc1 = g4.y * rsqrtf(v4.y + 1e-5f);
    float sc2 = g4.z * rsqrtf(v4.z + 1e-5f);
    float sc3 = g4.w * rsqrtf(v4.w + 1e-5f);
    float y0 = fmaxf(fmaf(sc0, s0, fmaf(sc0, bi4.x - m4.x, be4.x)), 0.f);
    float y1 = fmaxf(fmaf(sc1, s1, fmaf(sc1, bi4.y - m4.y, be4.y)), 0.f);
    float y2 = fmaxf(fmaf(sc2, s2, fmaf(sc2, bi4.z - m4.z, be4.z)), 0.f);
    float y3 = fmaxf(fmaf(sc3, s3, fmaf(sc3, bi4.w - m4.w, be4.w)), 0.f);
    {   // swizzled LDS store: 16B unit (l5>>1) ^ nl, 8B half (l5&1)
        int unit = (l5 >> 1) ^ nl;
        uint2* p = (uint2*)&hl[nl][(unit << 2) + ((l5 & 1) << 1)];
        *p = make_uint2(pack2(y0, y1), pack2(y2, y3));
    }
    __syncthreads();

    // ---- GEMM phase ----
    int w = tid >> 6;
    if (w < NCT) {
        int l = tid & 63;
        int r = l & 15, hi = l >> 4;
        f32x4 acc = (f32x4)(0.f);
        const uint4* wp = (const uint4*)Wpk;
#pragma unroll
        for (int ks = 0; ks < 4; ++ks) {
            int unit = (ks * 4 + hi) ^ r;
            uint4 a = *(const uint4*)&hl[r][unit << 2];
            s16x8 afrag = *(s16x8*)&a;
            uint4 b = wp[(ks * NCT + w) * 64 + l];
            s16x8 bfrag = *(s16x8*)&b;
            acc = __builtin_amdgcn_mfma_f32_16x16x32_bf16(afrag, bfrag, acc, 0, 0, 0);
        }
        int nbase = blockIdx.x * 16;
#pragma unroll
        for (int reg = 0; reg < 4; ++reg) {
            int orow = nbase + 4 * hi + reg;
            int oc = w * 16 + r;
            if (orow < n && (NCT == 8 || oc < 40))
                O[(size_t)orow * ostride + oc] = f2bf(dinv[orow] * acc[reg]);
        }
    }
}

// ------------------------------ final agg40 --------------------------------

// d=40 bf16 gather-sum + bias + log_softmax; 2 nodes/wave, 20 lanes x 2 feats.
__global__ __launch_bounds__(256) void k_agg40(const u16* __restrict__ X,
                                               float* __restrict__ out,
                                               const int* __restrict__ row,
                                               const int* __restrict__ col,
                                               const float* __restrict__ dinv,
                                               const float* __restrict__ b2,
                                               int n) {
    int tid = threadIdx.x;
    int wid = tid >> 6, lane = tid & 63;
    int half = lane >> 5, l5 = lane & 31;
    int node = (blockIdx.x * 4 + wid) * 2 + half;
    bool valid = node < n;
    int nc = valid ? node : (n - 1);
    bool active = l5 < 20;
    const u32* xp = (const u32*)X;  // 20 u32 per row
    int s = row[nc], e = row[nc + 1];
    int li = min(l5, 19);
    float a0 = 0, a1 = 0, b0 = 0, b1 = 0, c0 = 0, c1 = 0, d0 = 0, d1 = 0;
    {
        u32 v = xp[(size_t)nc * 20 + li];
        a0 = bflo(v); a1 = bfhi(v);
    }
    int j = s;
    for (; j + 8 <= e; j += 8) {
        int e0 = col[j], e1 = col[j+1], e2 = col[j+2], e3 = col[j+3];
        int e4 = col[j+4], e5 = col[j+5], e6 = col[j+6], e7 = col[j+7];
        u32 x0 = xp[(size_t)e0 * 20 + li];
        u32 x1 = xp[(size_t)e1 * 20 + li];
        u32 x2 = xp[(size_t)e2 * 20 + li];
        u32 x3 = xp[(size_t)e3 * 20 + li];
        u32 x4 = xp[(size_t)e4 * 20 + li];
        u32 x5 = xp[(size_t)e5 * 20 + li];
        u32 x6 = xp[(size_t)e6 * 20 + li];
        u32 x7 = xp[(size_t)e7 * 20 + li];
        a0 += bflo(x0); a1 += bfhi(x0);
        b0 += bflo(x1); b1 += bfhi(x1);
        c0 += bflo(x2); c1 += bfhi(x2);
        d0 += bflo(x3); d1 += bfhi(x3);
        a0 += bflo(x4); a1 += bfhi(x4);
        b0 += bflo(x5); b1 += bfhi(x5);
        c0 += bflo(x6); c1 += bfhi(x6);
        d0 += bflo(x7); d1 += bfhi(x7);
    }
    for (; j + 2 <= e; j += 2) {
        int e0 = col[j], e1 = col[j+1];
        u32 x0 = xp[(size_t)e0 * 20 + li];
        u32 x1 = xp[(size_t)e1 * 20 + li];
        a0 += bflo(x0); a1 += bfhi(x0);
        b0 += bflo(x1); b1 += bfhi(x1);
    }
    if (j < e) {
        u32 x0 = xp[(size_t)col[j] * 20 + li];
        c0 += bflo(x0); c1 += bfhi(x0);
    }
    float dv = dinv[nc];
    float ylo = -INFINITY, yhi = -INFINITY;
    if (active) {
        float2 bb = ((const float2*)b2)[l5];
        ylo = fmaf(dv, (a0 + b0) + (c0 + d0), bb.x);
        yhi = fmaf(dv, (a1 + b1) + (c1 + d1), bb.y);
    }
    float m = fmaxf(ylo, yhi);
#pragma unroll
    for (int d = 16; d; d >>= 1) m = fmaxf(m, __shfl_xor(m, d));
    float ex = active ? (__expf(ylo - m) + __expf(yhi - m)) : 0.f;
#pragma unroll
    for (int d = 16; d; d >>= 1) ex += __shfl_xor(ex, d);
    if (valid && active) {
        float lse = m + __logf(ex);
        ((float2*)out)[(size_t)node * 20 + l5] = make_float2(ylo - lse, yhi - lse);
    }
}

// --------------------------------- launch ----------------------------------

extern "C" void kernel_launch(void* const* d_in, const int* in_sizes, int n_in,
                              void* d_out, int out_size, void* d_ws, size_t ws_size,
                              hipStream_t stream) {
    const float* x   = (const float*)d_in[0];
    const int*   ei  = (const int*)d_in[1];
    const float* W0  = (const float*)d_in[2];
    const float* b0  = (const float*)d_in[3];
    const float* W1  = (const float*)d_in[4];
    const float* b1  = (const float*)d_in[5];
    const float* W2  = (const float*)d_in[6];
    const float* b2  = (const float*)d_in[7];
    const float* g0  = (const float*)d_in[8];
    const float* be0 = (const float*)d_in[9];
    const float* m0  = (const float*)d_in[10];
    const float* v0  = (const float*)d_in[11];
    const float* g1  = (const float*)d_in[12];
    const float* be1 = (const float*)d_in[13];
    const float* m1  = (const float*)d_in[14];
    const float* v1  = (const float*)d_in[15];
    float* out = (float*)d_out;

    int N = in_sizes[0] / 128;
    int E = in_sizes[1] / 2;
    const int* src = ei;
    const int* dst = ei + E;

    int NB = (N + CSZ - 1) / CSZ;

    char* ws = (char*)d_ws;
    size_t off = 0;
    auto alloc = [&](size_t bytes) -> char* {
        char* p = ws + off;
        off += (bytes + 255) & ~(size_t)255;
        return p;
    };
    u16*   XsA   = (u16*)alloc((size_t)N * 128 * 2);
    u16*   XsB   = (u16*)alloc((size_t)N * 128 * 2);
    u16*   bufC  = (u16*)alloc((size_t)N * 40 * 2);
    int*   col   = (int*)alloc((size_t)E * 4 + 64);
    int*   row   = (int*)alloc((size_t)(N + 1) * 4);
    float* dinv  = (float*)alloc((size_t)N * 4);
    int*   hist1 = (int*)alloc((size_t)(NB + 1) * 4);
    int*   base1 = (int*)alloc((size_t)(NB + 1) * 4);
    int*   cur1  = (int*)alloc((size_t)(NB + 1) * 4);
    u16*   Wpk0  = (u16*)alloc(128 * 128 * 2);
    u16*   Wpk1  = (u16*)alloc(128 * 128 * 2);
    u16*   Wpk2  = (u16*)alloc(128 * 48 * 2);
    u32*   bkt   = (u32*)XsA;  // alias: bkt dead before gemm0 writes XsA

    hipMemsetAsync(hist1, 0, (size_t)(NB + 1) * 4, stream);
    k_hist1<<<(E + 4095) / 4096, 256, 0, stream>>>(dst, hist1, E, NB);
    k_scan1<<<1, 256, 0, stream>>>(hist1, base1, cur1, NB, E);
    k_part1<<<(E + PCHUNK - 1) / PCHUNK, 256, 0, stream>>>(src, dst, cur1, bkt, E, NB);
    k_csr<<<NB, 256, 0, stream>>>(bkt, base1, col, row, dinv, N, E);
    k_packW<<<64, 256, 0, stream>>>(W0, Wpk0);
    k_packW<<<64, 256, 0, stream>>>(W1, Wpk1);
    k_packW40<<<24, 256, 0, stream>>>(W2, Wpk2);

    int gemmGrid = ((N + 15) / 16 + 3) / 4;
    k_gemm0<<<gemmGrid, 256, 0, stream>>>(x, Wpk0, XsA, dinv, N);
    int fusedGrid = (N + 15) / 16;
    k_fused<8><<<fusedGrid, 512, 0, stream>>>(XsA, Wpk1, XsB, row, col, dinv,
                                              b0, g0, be0, m0, v0, N, 128);
    k_fused<3><<<fusedGrid, 512, 0, stream>>>(XsB, Wpk2, bufC, row, col, dinv,
                                              b1, g1, be1, m1, v1, N, 40);
    k_agg40<<<(N + 7) / 8, 256, 0, stream>>>(bufC, out, row, col, dinv, b2, N);
}